// Round 1
// baseline (2422.839 us; speedup 1.0000x reference)
//
#include <hip/hip_runtime.h>
#include <math.h>

#define NPROP 1000
#define CCH 256
#define FH 100
#define FW 100
#define POOLSZ 7
#define FEAT 12544   // 256*49
#define HID 1024
#define NCLS 21
#define NHEAD 105    // 21 + 84
#define NCAND 20000  // 1000 * 20
#define SCORE_T 0.05f
#define NMS_T 0.5f
#define MAXDET 100

// ---------------- transpose fm [256,100,100] -> fmT [100*100, 256] ----------------
__global__ __launch_bounds__(256) void k_transpose(const float* __restrict__ fm,
                                                   float* __restrict__ fmT) {
    __shared__ float lds[64 * 257];
    int posbase = blockIdx.x * 64;
    int tid = threadIdx.x;
    int cq = tid >> 6;   // 0..3
    int pl = tid & 63;   // 0..63
    int pos = posbase + pl;
    bool pok = pos < FH * FW;
    for (int c0 = 0; c0 < CCH; c0 += 4) {
        int c = c0 + cq;
        float v = pok ? fm[c * (FH * FW) + pos] : 0.f;
        lds[pl * 257 + c] = v;
    }
    __syncthreads();
    for (int p = 0; p < 64; ++p) {
        int pos2 = posbase + p;
        if (pos2 < FH * FW) fmT[(size_t)pos2 * CCH + tid] = lds[p * 257 + tid];
    }
}

// ---------------- ROI align: pooled [1000][12544], k = c*49 + py*7 + px ----------------
__global__ __launch_bounds__(256) void k_roi(const float* __restrict__ fmT,
                                             const float* __restrict__ rois,
                                             float* __restrict__ pooled) {
    int n = blockIdx.x;
    int tid = threadIdx.x;
    __shared__ float wx0[14], wx1[14], wy0[14], wy1[14];
    __shared__ int ix0[14], ix1[14], iy0[14], iy1[14], vx[14], vy[14];
    __shared__ float outb[FEAT];

    if (tid < 28) {
        int axis = tid / 14;  // 0=x, 1=y
        int j = tid % 14;
        float p0 = rois[n * 4 + axis];
        float p1 = rois[n * 4 + 2 + axis];
        float b0 = p0 * 0.125f - 0.5f;
        float b1 = p1 * 0.125f - 0.5f;
        float bsz = (b1 - b0) / 7.0f;
        int p = j >> 1, s = j & 1;
        float off = (float)p + ((float)s + 0.5f) / 2.0f;
        float v = b0 + off * bsz;
        float size = 100.0f;
        int valid = (v >= -1.0f && v <= size) ? 1 : 0;
        v = fminf(fmaxf(v, 0.0f), size - 1.0f);
        float v0 = floorf(v);
        int i0 = (int)v0;
        int i1 = min(i0 + 1, 99);
        float w1v = v - v0;
        float w0v = 1.0f - w1v;
        if (axis == 0) { ix0[j] = i0 * CCH; ix1[j] = i1 * CCH; wx0[j] = w0v; wx1[j] = w1v; vx[j] = valid; }
        else           { iy0[j] = i0 * (FW * CCH); iy1[j] = i1 * (FW * CCH); wy0[j] = w0v; wy1[j] = w1v; vy[j] = valid; }
    }
    __syncthreads();

    int c = tid;
    for (int py = 0; py < POOLSZ; ++py) {
        for (int px = 0; px < POOLSZ; ++px) {
            float acc = 0.f;
            #pragma unroll
            for (int sy = 0; sy < 2; ++sy) {
                int jy = py * 2 + sy;
                if (!vy[jy]) continue;
                float fy0 = wy0[jy], fy1 = wy1[jy];
                int y0 = iy0[jy], y1 = iy1[jy];
                #pragma unroll
                for (int sx = 0; sx < 2; ++sx) {
                    int jx = px * 2 + sx;
                    if (!vx[jx]) continue;
                    float fx0 = wx0[jx], fx1 = wx1[jx];
                    int x0 = ix0[jx], x1 = ix1[jx];
                    float a00 = fmT[y0 + x0 + c];
                    float a01 = fmT[y0 + x1 + c];
                    float a10 = fmT[y1 + x0 + c];
                    float a11 = fmT[y1 + x1 + c];
                    acc += fy0 * (fx0 * a00 + fx1 * a01) + fy1 * (fx0 * a10 + fx1 * a11);
                }
            }
            outb[c * 49 + py * 7 + px] = acc * 0.25f;
        }
    }
    __syncthreads();
    size_t base = (size_t)n * FEAT;
    for (int o = tid; o < FEAT; o += 256)
        pooled[base + o] = outb[o];
}

// ---------------- fp32 GEMM: C[M,N] = relu?(A[M,K] @ B[K,N] + bias[N]) ----------------
// 64x64 tile, BK=32, 256 threads, 4x4 per thread, LDS double-buffer.
__global__ __launch_bounds__(256) void k_gemm(const float* __restrict__ A,
                                              const float* __restrict__ B,
                                              const float* __restrict__ bias,
                                              float* __restrict__ C,
                                              int M, int Nn, int K, int relu) {
    __shared__ float As[2][32 * 68];
    __shared__ float Bs[2][32 * 64];
    int tid = threadIdx.x;
    int n0 = blockIdx.x * 64;
    int m0 = blockIdx.y * 64;
    int tx = tid & 15, ty = tid >> 4;
    int ar = tid >> 2, ac4 = tid & 3;   // A load: 64 rows x 4 float4-cols
    int bk = tid >> 4, bc4 = tid & 15;  // B load: 16 k-rows x 16 float4-cols
    float acc[4][4] = {};
    float4 aReg[2], bReg[2];
    int nt = K >> 5;

    // ---- load tile 0 ----
    {
        int row = m0 + ar;
        const float* p = A + (size_t)row * K;
        #pragma unroll
        for (int j = 0; j < 2; ++j) {
            int kc = ac4 * 4 + j * 16;
            aReg[j] = (row < M) ? *(const float4*)(p + kc) : make_float4(0.f, 0.f, 0.f, 0.f);
            bReg[j] = *(const float4*)(B + (size_t)(bk + j * 16) * Nn + n0 + bc4 * 4);
        }
        // store buf 0
        #pragma unroll
        for (int j = 0; j < 2; ++j) {
            float tmp[4] = {aReg[j].x, aReg[j].y, aReg[j].z, aReg[j].w};
            #pragma unroll
            for (int e = 0; e < 4; ++e)
                As[0][(ac4 * 4 + j * 16 + e) * 68 + ar] = tmp[e];
            *(float4*)&Bs[0][(bk + j * 16) * 64 + bc4 * 4] = bReg[j];
        }
    }
    __syncthreads();

    for (int t = 0; t < nt; ++t) {
        int cur = t & 1, nxt = cur ^ 1;
        if (t + 1 < nt) {
            int k0 = (t + 1) << 5;
            int row = m0 + ar;
            const float* p = A + (size_t)row * K + k0;
            #pragma unroll
            for (int j = 0; j < 2; ++j) {
                int kc = ac4 * 4 + j * 16;
                aReg[j] = (row < M) ? *(const float4*)(p + kc) : make_float4(0.f, 0.f, 0.f, 0.f);
                bReg[j] = *(const float4*)(B + (size_t)(k0 + bk + j * 16) * Nn + n0 + bc4 * 4);
            }
        }
        // compute on cur
        #pragma unroll
        for (int kk = 0; kk < 32; ++kk) {
            float4 av = *(const float4*)&As[cur][kk * 68 + ty * 4];
            float4 bv = *(const float4*)&Bs[cur][kk * 64 + tx * 4];
            float a_[4] = {av.x, av.y, av.z, av.w};
            float b_[4] = {bv.x, bv.y, bv.z, bv.w};
            #pragma unroll
            for (int i = 0; i < 4; ++i)
                #pragma unroll
                for (int jj = 0; jj < 4; ++jj)
                    acc[i][jj] = fmaf(a_[i], b_[jj], acc[i][jj]);
        }
        if (t + 1 < nt) {
            #pragma unroll
            for (int j = 0; j < 2; ++j) {
                float tmp[4] = {aReg[j].x, aReg[j].y, aReg[j].z, aReg[j].w};
                #pragma unroll
                for (int e = 0; e < 4; ++e)
                    As[nxt][(ac4 * 4 + j * 16 + e) * 68 + ar] = tmp[e];
                *(float4*)&Bs[nxt][(bk + j * 16) * 64 + bc4 * 4] = bReg[j];
            }
            __syncthreads();
        }
    }

    // epilogue
    #pragma unroll
    for (int i = 0; i < 4; ++i) {
        int row = m0 + ty * 4 + i;
        if (row < M) {
            float4 v;
            float* vp = (float*)&v;
            #pragma unroll
            for (int jj = 0; jj < 4; ++jj) {
                float x = acc[i][jj] + bias[n0 + tx * 4 + jj];
                if (relu) x = fmaxf(x, 0.f);
                vp[jj] = x;
            }
            *(float4*)&C[(size_t)row * Nn + n0 + tx * 4] = v;
        }
    }
}

// ---------------- heads: logits[1000][105] = x2 @ [wc|wb] + [bc|bb] ----------------
__global__ __launch_bounds__(128) void k_heads(const float* __restrict__ x2,
                                               const float* __restrict__ wc,
                                               const float* __restrict__ bc,
                                               const float* __restrict__ wb,
                                               const float* __restrict__ bb,
                                               float* __restrict__ logits) {
    int r0 = blockIdx.x * 4;
    __shared__ float xs[4][HID];
    for (int i = threadIdx.x; i < 4 * HID; i += 128) {
        int rr = i >> 10, kk = i & 1023;
        xs[rr][kk] = x2[(size_t)(r0 + rr) * HID + kk];
    }
    __syncthreads();
    int j = threadIdx.x;
    if (j < NHEAD) {
        float a0 = 0.f, a1 = 0.f, a2 = 0.f, a3 = 0.f;
        if (j < NCLS) {
            for (int k = 0; k < HID; ++k) {
                float w = wc[k * NCLS + j];
                a0 = fmaf(xs[0][k], w, a0);
                a1 = fmaf(xs[1][k], w, a1);
                a2 = fmaf(xs[2][k], w, a2);
                a3 = fmaf(xs[3][k], w, a3);
            }
            float b = bc[j];
            a0 += b; a1 += b; a2 += b; a3 += b;
        } else {
            int jb = j - NCLS;
            for (int k = 0; k < HID; ++k) {
                float w = wb[k * 84 + jb];
                a0 = fmaf(xs[0][k], w, a0);
                a1 = fmaf(xs[1][k], w, a1);
                a2 = fmaf(xs[2][k], w, a2);
                a3 = fmaf(xs[3][k], w, a3);
            }
            float b = bb[jb];
            a0 += b; a1 += b; a2 += b; a3 += b;
        }
        logits[(size_t)(r0 + 0) * NHEAD + j] = a0;
        logits[(size_t)(r0 + 1) * NHEAD + j] = a1;
        logits[(size_t)(r0 + 2) * NHEAD + j] = a2;
        logits[(size_t)(r0 + 3) * NHEAD + j] = a3;
    }
}

// ---------------- softmax + decode + candidate scores ----------------
__global__ __launch_bounds__(256) void k_prep(const float* __restrict__ logits,
                                              const float* __restrict__ rois,
                                              float* __restrict__ boxes,
                                              float* __restrict__ cand) {
    int n = blockIdx.x * 256 + threadIdx.x;
    if (n >= NPROP) return;
    const float* L = logits + (size_t)n * NHEAD;
    float m = L[0];
    #pragma unroll
    for (int k = 1; k < NCLS; ++k) m = fmaxf(m, L[k]);
    float sum = 0.f;
    #pragma unroll
    for (int k = 0; k < NCLS; ++k) sum += expf(L[k] - m);

    float p0 = rois[n * 4 + 0], p1 = rois[n * 4 + 1];
    float p2 = rois[n * 4 + 2], p3 = rois[n * 4 + 3];
    float w = p2 - p0, h = p3 - p1;
    float cx = p0 + 0.5f * w, cy = p1 + 0.5f * h;

    for (int k = 1; k < NCLS; ++k) {
        int i = n * 20 + (k - 1);
        float s = expf(L[k] - m) / sum;
        const float* D = L + NCLS + k * 4;
        float dx = D[0], dy = D[1], dw = D[2], dh = D[3];
        float pcx = dx * w + cx;
        float pcy = dy * h + cy;
        float pw = expf(dw) * w;
        float ph = expf(dh) * h;
        boxes[(size_t)i * 4 + 0] = pcx - 0.5f * pw;
        boxes[(size_t)i * 4 + 1] = pcy - 0.5f * ph;
        boxes[(size_t)i * 4 + 2] = pcx + 0.5f * pw;
        boxes[(size_t)i * 4 + 3] = pcy + 0.5f * ph;
        cand[i] = (s > SCORE_T) ? s : -__builtin_inff();
    }
}

// ---------------- NMS: single block, exact reference semantics ----------------
__global__ __launch_bounds__(1024) void k_nms(const float* __restrict__ cand,
                                              const float* __restrict__ boxes,
                                              float* __restrict__ out) {
    __shared__ float sc[NCAND];
    __shared__ float wsc[16];
    __shared__ int widx[16];
    __shared__ float bestS;
    __shared__ int bestI;
    __shared__ float bbox[4];
    int tid = threadIdx.x;
    for (int i = tid; i < NCAND; i += 1024) sc[i] = cand[i];
    int lo = tid * 20;
    int hi = lo + 20;
    if (lo > NCAND) lo = NCAND;
    if (hi > NCAND) hi = NCAND;
    __syncthreads();

    for (int it = 0; it < MAXDET; ++it) {
        float ls = -__builtin_inff();
        int li = -1;
        for (int i = lo; i < hi; ++i) {
            float s = sc[i];
            if (s > ls) { ls = s; li = i; }  // ascending scan + strict > == first-max
        }
        #pragma unroll
        for (int off = 32; off > 0; off >>= 1) {
            float os = __shfl_down(ls, off);
            int oi = __shfl_down(li, off);
            if (os > ls || (os == ls && oi != -1 && (li == -1 || oi < li))) { ls = os; li = oi; }
        }
        if ((tid & 63) == 0) { wsc[tid >> 6] = ls; widx[tid >> 6] = li; }
        __syncthreads();
        if (tid == 0) {
            float bs = wsc[0]; int bi = widx[0];
            for (int w2 = 1; w2 < 16; ++w2) {
                float s2 = wsc[w2]; int i2 = widx[w2];
                if (s2 > bs || (s2 == bs && i2 != -1 && (bi == -1 || i2 < bi))) { bs = s2; bi = i2; }
            }
            bool valid = (bi >= 0) && (bs > SCORE_T);
            if (valid) {
                int lab = bi % 20 + 1;
                float b0 = boxes[(size_t)bi * 4 + 0];
                float b1 = boxes[(size_t)bi * 4 + 1];
                float b2 = boxes[(size_t)bi * 4 + 2];
                float b3 = boxes[(size_t)bi * 4 + 3];
                out[it * 4 + 0] = b0; out[it * 4 + 1] = b1;
                out[it * 4 + 2] = b2; out[it * 4 + 3] = b3;
                out[400 + it] = bs;
                out[500 + it] = (float)lab;
                float offv = (float)lab * 10000.0f;  // same f32 op as reference boxes_off
                bbox[0] = b0 + offv; bbox[1] = b1 + offv;
                bbox[2] = b2 + offv; bbox[3] = b3 + offv;
                bestS = bs;
            } else {
                out[it * 4 + 0] = 0.f; out[it * 4 + 1] = 0.f;
                out[it * 4 + 2] = 0.f; out[it * 4 + 3] = 0.f;
                out[400 + it] = 0.f;
                out[500 + it] = 0.f;
                bestS = -__builtin_inff();
            }
            bestI = bi;
        }
        __syncthreads();
        if (bestS > SCORE_T) {
            float q0 = bbox[0], q1 = bbox[1], q2 = bbox[2], q3 = bbox[3];
            float qa = (q2 - q0) * (q3 - q1);
            for (int i = lo; i < hi; ++i) {
                float s = sc[i];
                if (s == -__builtin_inff()) continue;
                int lab = i % 20 + 1;
                float offv = (float)lab * 10000.0f;
                float c0 = boxes[(size_t)i * 4 + 0] + offv;
                float c1 = boxes[(size_t)i * 4 + 1] + offv;
                float c2 = boxes[(size_t)i * 4 + 2] + offv;
                float c3 = boxes[(size_t)i * 4 + 3] + offv;
                float ix1 = fmaxf(q0, c0), iy1 = fmaxf(q1, c1);
                float ix2 = fminf(q2, c2), iy2 = fminf(q3, c3);
                float inter = fmaxf(ix2 - ix1, 0.f) * fmaxf(iy2 - iy1, 0.f);
                float A2 = (c2 - c0) * (c3 - c1);
                float iou = inter / (qa + A2 - inter + 1e-9f);
                if (iou > NMS_T) sc[i] = -__builtin_inff();
            }
        }
        __syncthreads();
    }
}

extern "C" void kernel_launch(void* const* d_in, const int* in_sizes, int n_in,
                              void* d_out, int out_size, void* d_ws, size_t ws_size,
                              hipStream_t stream) {
    const float* fm   = (const float*)d_in[0];
    const float* rois = (const float*)d_in[1];
    const float* w1   = (const float*)d_in[2];
    const float* b1   = (const float*)d_in[3];
    const float* w2   = (const float*)d_in[4];
    const float* b2   = (const float*)d_in[5];
    const float* wc   = (const float*)d_in[6];
    const float* bc   = (const float*)d_in[7];
    const float* wb   = (const float*)d_in[8];
    const float* bb   = (const float*)d_in[9];
    float* out = (float*)d_out;

    float* ws = (float*)d_ws;
    float* fmT    = ws;                       // 2,560,000
    float* pooled = fmT + 2560000;            // 12,544,000
    float* x1     = pooled + 12544000;        // 1,024,000
    float* x2     = x1 + 1024000;             // 1,024,000
    float* logits = x2 + 1024000;             // 105,000
    float* boxes  = logits + 105000;          // 80,000
    float* cand   = boxes + 80000;            // 20,000

    k_transpose<<<157, 256, 0, stream>>>(fm, fmT);
    k_roi<<<NPROP, 256, 0, stream>>>(fmT, rois, pooled);
    k_gemm<<<dim3(16, 16), 256, 0, stream>>>(pooled, w1, b1, x1, NPROP, HID, FEAT, 1);
    k_gemm<<<dim3(16, 16), 256, 0, stream>>>(x1, w2, b2, x2, NPROP, HID, HID, 1);
    k_heads<<<250, 128, 0, stream>>>(x2, wc, bc, wb, bb, logits);
    k_prep<<<4, 256, 0, stream>>>(logits, rois, boxes, cand);
    k_nms<<<1, 1024, 0, stream>>>(cand, boxes, out);
}

// Round 2
// 2061.775 us; speedup vs baseline: 1.1751x; 1.1751x over previous
//
#include <hip/hip_runtime.h>
#include <math.h>

#define NPROP 1000
#define CCH 256
#define FH 100
#define FW 100
#define POOLSZ 7
#define FEAT 12544   // 256*49
#define HID 1024
#define NCLS 21
#define NHEAD 105    // 21 + 84
#define NCAND 20000  // 1000 * 20
#define SCORE_T 0.05f
#define NMS_T 0.5f
#define MAXDET 100
#define NMS_CAP 8192

// ---------------- transpose fm [256,100,100] -> fmT [100*100, 256] ----------------
__global__ __launch_bounds__(256) void k_transpose(const float* __restrict__ fm,
                                                   float* __restrict__ fmT) {
    __shared__ float lds[64 * 257];
    int posbase = blockIdx.x * 64;
    int tid = threadIdx.x;
    int cq = tid >> 6;   // 0..3
    int pl = tid & 63;   // 0..63
    int pos = posbase + pl;
    bool pok = pos < FH * FW;
    for (int c0 = 0; c0 < CCH; c0 += 4) {
        int c = c0 + cq;
        float v = pok ? fm[c * (FH * FW) + pos] : 0.f;
        lds[pl * 257 + c] = v;
    }
    __syncthreads();
    for (int p = 0; p < 64; ++p) {
        int pos2 = posbase + p;
        if (pos2 < FH * FW) fmT[(size_t)pos2 * CCH + tid] = lds[p * 257 + tid];
    }
}

// ---------------- ROI align: pooled [1000][12544], k = c*49 + py*7 + px ----------------
__global__ __launch_bounds__(256) void k_roi(const float* __restrict__ fmT,
                                             const float* __restrict__ rois,
                                             float* __restrict__ pooled) {
    int n = blockIdx.x;
    int tid = threadIdx.x;
    __shared__ float wx0[14], wx1[14], wy0[14], wy1[14];
    __shared__ int ix0[14], ix1[14], iy0[14], iy1[14], vx[14], vy[14];
    __shared__ float outb[FEAT];

    if (tid < 28) {
        int axis = tid / 14;  // 0=x, 1=y
        int j = tid % 14;
        float p0 = rois[n * 4 + axis];
        float p1 = rois[n * 4 + 2 + axis];
        float b0 = p0 * 0.125f - 0.5f;
        float b1 = p1 * 0.125f - 0.5f;
        float bsz = (b1 - b0) / 7.0f;
        int p = j >> 1, s = j & 1;
        float off = (float)p + ((float)s + 0.5f) / 2.0f;
        float v = b0 + off * bsz;
        float size = 100.0f;
        int valid = (v >= -1.0f && v <= size) ? 1 : 0;
        v = fminf(fmaxf(v, 0.0f), size - 1.0f);
        float v0 = floorf(v);
        int i0 = (int)v0;
        int i1 = min(i0 + 1, 99);
        float w1v = v - v0;
        float w0v = 1.0f - w1v;
        if (axis == 0) { ix0[j] = i0 * CCH; ix1[j] = i1 * CCH; wx0[j] = w0v; wx1[j] = w1v; vx[j] = valid; }
        else           { iy0[j] = i0 * (FW * CCH); iy1[j] = i1 * (FW * CCH); wy0[j] = w0v; wy1[j] = w1v; vy[j] = valid; }
    }
    __syncthreads();

    int c = tid;
    for (int py = 0; py < POOLSZ; ++py) {
        for (int px = 0; px < POOLSZ; ++px) {
            float acc = 0.f;
            #pragma unroll
            for (int sy = 0; sy < 2; ++sy) {
                int jy = py * 2 + sy;
                if (!vy[jy]) continue;
                float fy0 = wy0[jy], fy1 = wy1[jy];
                int y0 = iy0[jy], y1 = iy1[jy];
                #pragma unroll
                for (int sx = 0; sx < 2; ++sx) {
                    int jx = px * 2 + sx;
                    if (!vx[jx]) continue;
                    float fx0 = wx0[jx], fx1 = wx1[jx];
                    int x0 = ix0[jx], x1 = ix1[jx];
                    float a00 = fmT[y0 + x0 + c];
                    float a01 = fmT[y0 + x1 + c];
                    float a10 = fmT[y1 + x0 + c];
                    float a11 = fmT[y1 + x1 + c];
                    acc += fy0 * (fx0 * a00 + fx1 * a01) + fy1 * (fx0 * a10 + fx1 * a11);
                }
            }
            outb[c * 49 + py * 7 + px] = acc * 0.25f;
        }
    }
    __syncthreads();
    size_t base = (size_t)n * FEAT;
    for (int o = tid; o < FEAT; o += 256)
        pooled[base + o] = outb[o];
}

// ---------------- fp32 GEMM: C[M,N] = relu?(A[M,K] @ B[K,N] + bias[N]) ----------------
// 64x64 tile, BK=32, 256 threads, 4x4 per thread, LDS double-buffer.
__global__ __launch_bounds__(256) void k_gemm(const float* __restrict__ A,
                                              const float* __restrict__ B,
                                              const float* __restrict__ bias,
                                              float* __restrict__ C,
                                              int M, int Nn, int K, int relu) {
    __shared__ float As[2][32 * 68];
    __shared__ float Bs[2][32 * 64];
    int tid = threadIdx.x;
    int n0 = blockIdx.x * 64;
    int m0 = blockIdx.y * 64;
    int tx = tid & 15, ty = tid >> 4;
    int ar = tid >> 2, ac4 = tid & 3;   // A load: 64 rows x 4 float4-cols
    int bk = tid >> 4, bc4 = tid & 15;  // B load: 16 k-rows x 16 float4-cols
    float acc[4][4] = {};
    float4 aReg[2], bReg[2];
    int nt = K >> 5;

    // ---- load tile 0 ----
    {
        int row = m0 + ar;
        const float* p = A + (size_t)row * K;
        #pragma unroll
        for (int j = 0; j < 2; ++j) {
            int kc = ac4 * 4 + j * 16;
            aReg[j] = (row < M) ? *(const float4*)(p + kc) : make_float4(0.f, 0.f, 0.f, 0.f);
            bReg[j] = *(const float4*)(B + (size_t)(bk + j * 16) * Nn + n0 + bc4 * 4);
        }
        // store buf 0
        #pragma unroll
        for (int j = 0; j < 2; ++j) {
            float tmp[4] = {aReg[j].x, aReg[j].y, aReg[j].z, aReg[j].w};
            #pragma unroll
            for (int e = 0; e < 4; ++e)
                As[0][(ac4 * 4 + j * 16 + e) * 68 + ar] = tmp[e];
            *(float4*)&Bs[0][(bk + j * 16) * 64 + bc4 * 4] = bReg[j];
        }
    }
    __syncthreads();

    for (int t = 0; t < nt; ++t) {
        int cur = t & 1, nxt = cur ^ 1;
        if (t + 1 < nt) {
            int k0 = (t + 1) << 5;
            int row = m0 + ar;
            const float* p = A + (size_t)row * K + k0;
            #pragma unroll
            for (int j = 0; j < 2; ++j) {
                int kc = ac4 * 4 + j * 16;
                aReg[j] = (row < M) ? *(const float4*)(p + kc) : make_float4(0.f, 0.f, 0.f, 0.f);
                bReg[j] = *(const float4*)(B + (size_t)(k0 + bk + j * 16) * Nn + n0 + bc4 * 4);
            }
        }
        // compute on cur
        #pragma unroll
        for (int kk = 0; kk < 32; ++kk) {
            float4 av = *(const float4*)&As[cur][kk * 68 + ty * 4];
            float4 bv = *(const float4*)&Bs[cur][kk * 64 + tx * 4];
            float a_[4] = {av.x, av.y, av.z, av.w};
            float b_[4] = {bv.x, bv.y, bv.z, bv.w};
            #pragma unroll
            for (int i = 0; i < 4; ++i)
                #pragma unroll
                for (int jj = 0; jj < 4; ++jj)
                    acc[i][jj] = fmaf(a_[i], b_[jj], acc[i][jj]);
        }
        if (t + 1 < nt) {
            #pragma unroll
            for (int j = 0; j < 2; ++j) {
                float tmp[4] = {aReg[j].x, aReg[j].y, aReg[j].z, aReg[j].w};
                #pragma unroll
                for (int e = 0; e < 4; ++e)
                    As[nxt][(ac4 * 4 + j * 16 + e) * 68 + ar] = tmp[e];
                *(float4*)&Bs[nxt][(bk + j * 16) * 64 + bc4 * 4] = bReg[j];
            }
            __syncthreads();
        }
    }

    // epilogue
    #pragma unroll
    for (int i = 0; i < 4; ++i) {
        int row = m0 + ty * 4 + i;
        if (row < M) {
            float4 v;
            float* vp = (float*)&v;
            #pragma unroll
            for (int jj = 0; jj < 4; ++jj) {
                float x = acc[i][jj] + bias[n0 + tx * 4 + jj];
                if (relu) x = fmaxf(x, 0.f);
                vp[jj] = x;
            }
            *(float4*)&C[(size_t)row * Nn + n0 + tx * 4] = v;
        }
    }
}

// ---------------- heads: logits[1000][105] = x2 @ [wc|wb] + [bc|bb] ----------------
__global__ __launch_bounds__(128) void k_heads(const float* __restrict__ x2,
                                               const float* __restrict__ wc,
                                               const float* __restrict__ bc,
                                               const float* __restrict__ wb,
                                               const float* __restrict__ bb,
                                               float* __restrict__ logits) {
    int r0 = blockIdx.x * 4;
    __shared__ float xs[4][HID];
    for (int i = threadIdx.x; i < 4 * HID; i += 128) {
        int rr = i >> 10, kk = i & 1023;
        xs[rr][kk] = x2[(size_t)(r0 + rr) * HID + kk];
    }
    __syncthreads();
    int j = threadIdx.x;
    if (j < NHEAD) {
        float a0 = 0.f, a1 = 0.f, a2 = 0.f, a3 = 0.f;
        if (j < NCLS) {
            for (int k = 0; k < HID; ++k) {
                float w = wc[k * NCLS + j];
                a0 = fmaf(xs[0][k], w, a0);
                a1 = fmaf(xs[1][k], w, a1);
                a2 = fmaf(xs[2][k], w, a2);
                a3 = fmaf(xs[3][k], w, a3);
            }
            float b = bc[j];
            a0 += b; a1 += b; a2 += b; a3 += b;
        } else {
            int jb = j - NCLS;
            for (int k = 0; k < HID; ++k) {
                float w = wb[k * 84 + jb];
                a0 = fmaf(xs[0][k], w, a0);
                a1 = fmaf(xs[1][k], w, a1);
                a2 = fmaf(xs[2][k], w, a2);
                a3 = fmaf(xs[3][k], w, a3);
            }
            float b = bb[jb];
            a0 += b; a1 += b; a2 += b; a3 += b;
        }
        logits[(size_t)(r0 + 0) * NHEAD + j] = a0;
        logits[(size_t)(r0 + 1) * NHEAD + j] = a1;
        logits[(size_t)(r0 + 2) * NHEAD + j] = a2;
        logits[(size_t)(r0 + 3) * NHEAD + j] = a3;
    }
}

// ---------------- softmax + decode + candidate scores ----------------
__global__ __launch_bounds__(256) void k_prep(const float* __restrict__ logits,
                                              const float* __restrict__ rois,
                                              float* __restrict__ boxes,
                                              float* __restrict__ cand) {
    int n = blockIdx.x * 256 + threadIdx.x;
    if (n >= NPROP) return;
    const float* L = logits + (size_t)n * NHEAD;
    float m = L[0];
    #pragma unroll
    for (int k = 1; k < NCLS; ++k) m = fmaxf(m, L[k]);
    float sum = 0.f;
    #pragma unroll
    for (int k = 0; k < NCLS; ++k) sum += expf(L[k] - m);

    float p0 = rois[n * 4 + 0], p1 = rois[n * 4 + 1];
    float p2 = rois[n * 4 + 2], p3 = rois[n * 4 + 3];
    float w = p2 - p0, h = p3 - p1;
    float cx = p0 + 0.5f * w, cy = p1 + 0.5f * h;

    for (int k = 1; k < NCLS; ++k) {
        int i = n * 20 + (k - 1);
        float s = expf(L[k] - m) / sum;
        const float* D = L + NCLS + k * 4;
        float dx = D[0], dy = D[1], dw = D[2], dh = D[3];
        float pcx = dx * w + cx;
        float pcy = dy * h + cy;
        float pw = expf(dw) * w;
        float ph = expf(dh) * h;
        boxes[(size_t)i * 4 + 0] = pcx - 0.5f * pw;
        boxes[(size_t)i * 4 + 1] = pcy - 0.5f * ph;
        boxes[(size_t)i * 4 + 2] = pcx + 0.5f * pw;
        boxes[(size_t)i * 4 + 3] = pcy + 0.5f * ph;
        cand[i] = (s > SCORE_T) ? s : -__builtin_inff();
    }
}

// ---------------- NMS: single block, register scores + LDS compacted boxes ----------------
// Selection key: (score_bits << 32) | (~idx)  — positive-float bits are monotonic,
// tie breaks to lowest index = jnp.argmax first-max semantics.
__global__ __launch_bounds__(1024) void k_nms(const float* __restrict__ cand,
                                              const float* __restrict__ boxes,
                                              float* __restrict__ out) {
    __shared__ float4 cb[NMS_CAP];           // compacted boxes_off (label*1e4 pre-added)
    __shared__ unsigned long long gkeys[2];  // ping-pong argmax keys
    __shared__ int cnt;
    __shared__ float sb[4];                  // winner box_off broadcast
    int tid = threadIdx.x;
    int base = tid * 20;
    if (tid == 0) cnt = 0;
    if (tid < 2) gkeys[tid] = 0ULL;
    __syncthreads();

    float s[20];
    int slot[20];
    #pragma unroll
    for (int i = 0; i < 20; ++i) {
        float v = cand[base + i];
        s[i] = v;
        slot[i] = -1;
        if (v > 0.0f) {                      // valid scores are > 0.05; invalid are -inf
            int sl = atomicAdd(&cnt, 1);
            slot[i] = sl;
            float offv = (float)(i + 1) * 10000.0f;  // label = i+1 (base is multiple of 20)
            if (sl < NMS_CAP) {
                float4 b;
                b.x = boxes[(size_t)(base + i) * 4 + 0] + offv;
                b.y = boxes[(size_t)(base + i) * 4 + 1] + offv;
                b.z = boxes[(size_t)(base + i) * 4 + 2] + offv;
                b.w = boxes[(size_t)(base + i) * 4 + 3] + offv;
                cb[sl] = b;
            }
        }
    }
    __syncthreads();

    int cur = 0;
    int it = 0;
    for (; it < MAXDET; ++it) {
        // --- scan (registers only) ---
        unsigned long long key = 0ULL;
        #pragma unroll
        for (int i = 0; i < 20; ++i) {
            if (s[i] > 0.0f) {
                unsigned long long k =
                    ((unsigned long long)__float_as_uint(s[i]) << 32) |
                    (unsigned long long)(0xFFFFFFFFu - (unsigned)(base + i));
                if (k > key) key = k;
            }
        }
        // --- wave reduce ---
        #pragma unroll
        for (int off = 32; off > 0; off >>= 1) {
            unsigned long long o = __shfl_down(key, off);
            if (o > key) key = o;
        }
        if ((tid & 63) == 0) atomicMax(&gkeys[cur], key);
        __syncthreads();  // A: argmax complete
        unsigned long long g = gkeys[cur];
        if (tid == 0) gkeys[cur ^ 1] = 0ULL;  // reset other buffer for next iter
        if (g != 0ULL) {
            int bi = (int)(0xFFFFFFFFu - (unsigned)(g & 0xFFFFFFFFu));
            if (bi / 20 == tid) {             // winner-owning thread writes outputs
                int li = bi - base;           // == bi % 20
                float bs = __uint_as_float((unsigned)(g >> 32));
                float b0 = boxes[(size_t)bi * 4 + 0];
                float b1 = boxes[(size_t)bi * 4 + 1];
                float b2 = boxes[(size_t)bi * 4 + 2];
                float b3 = boxes[(size_t)bi * 4 + 3];
                out[it * 4 + 0] = b0; out[it * 4 + 1] = b1;
                out[it * 4 + 2] = b2; out[it * 4 + 3] = b3;
                out[400 + it] = bs;
                out[500 + it] = (float)(li + 1);
                float offv = (float)(li + 1) * 10000.0f;
                sb[0] = b0 + offv; sb[1] = b1 + offv;
                sb[2] = b2 + offv; sb[3] = b3 + offv;
            }
        }
        __syncthreads();  // B: sb visible, reset visible
        if (g == 0ULL) break;   // uniform: no candidate > SCORE_T remains -> zeros forever

        // --- suppress (LDS float4 per live candidate) ---
        float q0 = sb[0], q1 = sb[1], q2 = sb[2], q3 = sb[3];
        float qa = (q2 - q0) * (q3 - q1);
        #pragma unroll
        for (int i = 0; i < 20; ++i) {
            if (s[i] > 0.0f) {
                float c0, c1, c2, c3;
                int sl = slot[i];
                if (sl < NMS_CAP) {
                    float4 b = cb[sl];
                    c0 = b.x; c1 = b.y; c2 = b.z; c3 = b.w;
                } else {
                    float offv = (float)(i + 1) * 10000.0f;
                    c0 = boxes[(size_t)(base + i) * 4 + 0] + offv;
                    c1 = boxes[(size_t)(base + i) * 4 + 1] + offv;
                    c2 = boxes[(size_t)(base + i) * 4 + 2] + offv;
                    c3 = boxes[(size_t)(base + i) * 4 + 3] + offv;
                }
                float ix1 = fmaxf(q0, c0), iy1 = fmaxf(q1, c1);
                float ix2 = fminf(q2, c2), iy2 = fminf(q3, c3);
                float inter = fmaxf(ix2 - ix1, 0.f) * fmaxf(iy2 - iy1, 0.f);
                float A2 = (c2 - c0) * (c3 - c1);
                float iou = inter / (qa + A2 - inter + 1e-9f);
                if (iou > NMS_T) s[i] = -__builtin_inff();
            }
        }
        cur ^= 1;
    }

    // zero-fill any remaining outputs (also runs when loop completed: empty ranges)
    for (int j = it * 4 + tid; j < 400; j += 1024) out[j] = 0.f;
    for (int j = 400 + it + tid; j < 500; j += 1024) out[j] = 0.f;
    for (int j = 500 + it + tid; j < 600; j += 1024) out[j] = 0.f;
}

extern "C" void kernel_launch(void* const* d_in, const int* in_sizes, int n_in,
                              void* d_out, int out_size, void* d_ws, size_t ws_size,
                              hipStream_t stream) {
    const float* fm   = (const float*)d_in[0];
    const float* rois = (const float*)d_in[1];
    const float* w1   = (const float*)d_in[2];
    const float* b1   = (const float*)d_in[3];
    const float* w2   = (const float*)d_in[4];
    const float* b2   = (const float*)d_in[5];
    const float* wc   = (const float*)d_in[6];
    const float* bc   = (const float*)d_in[7];
    const float* wb   = (const float*)d_in[8];
    const float* bb   = (const float*)d_in[9];
    float* out = (float*)d_out;

    float* ws = (float*)d_ws;
    float* fmT    = ws;                       // 2,560,000
    float* pooled = fmT + 2560000;            // 12,544,000
    float* x1     = pooled + 12544000;        // 1,024,000
    float* x2     = x1 + 1024000;             // 1,024,000
    float* logits = x2 + 1024000;             // 105,000
    float* boxes  = logits + 105000;          // 80,000
    float* cand   = boxes + 80000;            // 20,000

    k_transpose<<<157, 256, 0, stream>>>(fm, fmT);
    k_roi<<<NPROP, 256, 0, stream>>>(fmT, rois, pooled);
    k_gemm<<<dim3(16, 16), 256, 0, stream>>>(pooled, w1, b1, x1, NPROP, HID, FEAT, 1);
    k_gemm<<<dim3(16, 16), 256, 0, stream>>>(x1, w2, b2, x2, NPROP, HID, HID, 1);
    k_heads<<<250, 128, 0, stream>>>(x2, wc, bc, wb, bb, logits);
    k_prep<<<4, 256, 0, stream>>>(logits, rois, boxes, cand);
    k_nms<<<1, 1024, 0, stream>>>(cand, boxes, out);
}

// Round 3
// 1271.159 us; speedup vs baseline: 1.9060x; 1.6220x over previous
//
#include <hip/hip_runtime.h>
#include <math.h>

#define NPROP 1000
#define CCH 256
#define FH 100
#define FW 100
#define POOLSZ 7
#define FEAT 12544   // 256*49
#define HID 1024
#define NCLS 21
#define NHEAD 105    // 21 + 84
#define NCAND 20000  // 1000 * 20
#define SCORE_T 0.05f
#define NMS_T 0.5f
#define MAXDET 100
#define NMS_CAP 8192

typedef _Float16 f16;
typedef __attribute__((ext_vector_type(8))) _Float16 f16x8;
typedef __attribute__((ext_vector_type(4))) float f32x4;

// ---------------- transpose fm [256,100,100] -> fmT [100*100, 256] ----------------
__global__ __launch_bounds__(256) void k_transpose(const float* __restrict__ fm,
                                                   float* __restrict__ fmT) {
    __shared__ float lds[64 * 257];
    int posbase = blockIdx.x * 64;
    int tid = threadIdx.x;
    int cq = tid >> 6;   // 0..3
    int pl = tid & 63;   // 0..63
    int pos = posbase + pl;
    bool pok = pos < FH * FW;
    for (int c0 = 0; c0 < CCH; c0 += 4) {
        int c = c0 + cq;
        float v = pok ? fm[c * (FH * FW) + pos] : 0.f;
        lds[pl * 257 + c] = v;
    }
    __syncthreads();
    for (int p = 0; p < 64; ++p) {
        int pos2 = posbase + p;
        if (pos2 < FH * FW) fmT[(size_t)pos2 * CCH + tid] = lds[p * 257 + tid];
    }
}

// ---------------- ROI align: pooled [1000][12544], k = c*49 + py*7 + px ----------------
__global__ __launch_bounds__(256) void k_roi(const float* __restrict__ fmT,
                                             const float* __restrict__ rois,
                                             float* __restrict__ pooled) {
    int n = blockIdx.x;
    int tid = threadIdx.x;
    __shared__ float wx0[14], wx1[14], wy0[14], wy1[14];
    __shared__ int ix0[14], ix1[14], iy0[14], iy1[14], vx[14], vy[14];
    __shared__ float outb[FEAT];

    if (tid < 28) {
        int axis = tid / 14;  // 0=x, 1=y
        int j = tid % 14;
        float p0 = rois[n * 4 + axis];
        float p1 = rois[n * 4 + 2 + axis];
        float b0 = p0 * 0.125f - 0.5f;
        float b1 = p1 * 0.125f - 0.5f;
        float bsz = (b1 - b0) / 7.0f;
        int p = j >> 1, s = j & 1;
        float off = (float)p + ((float)s + 0.5f) / 2.0f;
        float v = b0 + off * bsz;
        float size = 100.0f;
        int valid = (v >= -1.0f && v <= size) ? 1 : 0;
        v = fminf(fmaxf(v, 0.0f), size - 1.0f);
        float v0 = floorf(v);
        int i0 = (int)v0;
        int i1 = min(i0 + 1, 99);
        float w1v = v - v0;
        float w0v = 1.0f - w1v;
        if (axis == 0) { ix0[j] = i0 * CCH; ix1[j] = i1 * CCH; wx0[j] = w0v; wx1[j] = w1v; vx[j] = valid; }
        else           { iy0[j] = i0 * (FW * CCH); iy1[j] = i1 * (FW * CCH); wy0[j] = w0v; wy1[j] = w1v; vy[j] = valid; }
    }
    __syncthreads();

    int c = tid;
    for (int py = 0; py < POOLSZ; ++py) {
        for (int px = 0; px < POOLSZ; ++px) {
            float acc = 0.f;
            #pragma unroll
            for (int sy = 0; sy < 2; ++sy) {
                int jy = py * 2 + sy;
                if (!vy[jy]) continue;
                float fy0 = wy0[jy], fy1 = wy1[jy];
                int y0 = iy0[jy], y1 = iy1[jy];
                #pragma unroll
                for (int sx = 0; sx < 2; ++sx) {
                    int jx = px * 2 + sx;
                    if (!vx[jx]) continue;
                    float fx0 = wx0[jx], fx1 = wx1[jx];
                    int x0 = ix0[jx], x1 = ix1[jx];
                    float a00 = fmT[y0 + x0 + c];
                    float a01 = fmT[y0 + x1 + c];
                    float a10 = fmT[y1 + x0 + c];
                    float a11 = fmT[y1 + x1 + c];
                    acc += fy0 * (fx0 * a00 + fx1 * a01) + fy1 * (fx0 * a10 + fx1 * a11);
                }
            }
            outb[c * 49 + py * 7 + px] = acc * 0.25f;
        }
    }
    __syncthreads();
    size_t base = (size_t)n * FEAT;
    for (int o = tid; o < FEAT; o += 256)
        pooled[base + o] = outb[o];
}

// ---------------- MFMA GEMM, f16 3-pass split (fp32-class accuracy) ----------------
// C_partial[kz][M=1024pad][1024] = A[M,K] @ B[K,1024] over kz's K-half.
// 64x64 tile, 4 waves of 32x32, K-step 32, LDS double-buffered.
// A-frag: m = lane&15 (rowblock*16+), k = 8*(lane>>4)+j
// B-frag: n = lane&15, same k.  D: col = lane&15, row = 4*(lane>>4)+r.
__global__ __launch_bounds__(256) void k_gemm_mfma(const float* __restrict__ A,
                                                   const float* __restrict__ B,
                                                   float* __restrict__ P,
                                                   int M, int K, int nt) {
    __shared__ f16 Ah[2][2048], Al[2][2048], Bh[2][2048], Bl[2][2048];
    int tid = threadIdx.x;
    int n0 = blockIdx.x * 64;
    int m0 = blockIdx.y * 64;
    int kz = blockIdx.z;
    int kbase0 = kz * nt * 32;

    int a_row = tid >> 2;   // 0..63
    int a_kq  = tid & 3;    // 0..3 (8 k's each)
    int b_n   = tid & 63;
    int b_kg  = tid >> 6;   // == wave id

    int wave = tid >> 6, lane = tid & 63;
    int wr = (wave >> 1) * 32, wc = (wave & 1) * 32;
    int lhi = lane >> 4, llo = lane & 15;

    f32x4 accm[2][2] = {};
    f32x4 accc[2][2] = {};

    float aS[8], bS[8];
    const float* Arow = A + (size_t)(m0 + a_row) * K;
    bool arow_ok = (m0 + a_row) < M;

    // LDS element indices (f16 units). A store is XOR-swizzled by kq.
    int a_st = a_kq * 512 + ((a_row ^ a_kq) << 3);
    int b_st = b_kg * 512 + (b_n << 3);
    int a_rd0 = lhi * 512 + (((wr + 0  + llo) ^ lhi) << 3);
    int a_rd1 = lhi * 512 + (((wr + 16 + llo) ^ lhi) << 3);
    int b_rd0 = lhi * 512 + ((wc + 0  + llo) << 3);
    int b_rd1 = lhi * 512 + ((wc + 16 + llo) << 3);

    auto LOAD = [&](int t) {
        int kb = kbase0 + t * 32;
        if (arow_ok) {
            const float* ap = Arow + kb + a_kq * 8;
            float4 v0 = *(const float4*)(ap);
            float4 v1 = *(const float4*)(ap + 4);
            aS[0] = v0.x; aS[1] = v0.y; aS[2] = v0.z; aS[3] = v0.w;
            aS[4] = v1.x; aS[5] = v1.y; aS[6] = v1.z; aS[7] = v1.w;
        } else {
            #pragma unroll
            for (int j = 0; j < 8; ++j) aS[j] = 0.f;
        }
        const float* bp = B + (size_t)(kb + b_kg * 8) * 1024 + n0 + b_n;
        #pragma unroll
        for (int j = 0; j < 8; ++j) bS[j] = bp[(size_t)j * 1024];
    };
    auto STORE = [&](int buf) {
        f16x8 vh, vl;
        #pragma unroll
        for (int j = 0; j < 8; ++j) {
            f16 h = (f16)aS[j];
            vh[j] = h;
            vl[j] = (f16)((aS[j] - (float)h) * 4096.0f);
        }
        *(f16x8*)&Ah[buf][a_st] = vh;
        *(f16x8*)&Al[buf][a_st] = vl;
        #pragma unroll
        for (int j = 0; j < 8; ++j) {
            f16 h = (f16)bS[j];
            vh[j] = h;
            vl[j] = (f16)((bS[j] - (float)h) * 4096.0f);
        }
        *(f16x8*)&Bh[buf][b_st] = vh;
        *(f16x8*)&Bl[buf][b_st] = vl;
    };

    LOAD(0);
    STORE(0);
    __syncthreads();

    for (int t = 0; t < nt; ++t) {
        int cur = t & 1;
        if (t + 1 < nt) LOAD(t + 1);
        {
            f16x8 ah0 = *(f16x8*)&Ah[cur][a_rd0];
            f16x8 ah1 = *(f16x8*)&Ah[cur][a_rd1];
            f16x8 bh0 = *(f16x8*)&Bh[cur][b_rd0];
            f16x8 bh1 = *(f16x8*)&Bh[cur][b_rd1];
            f16x8 al0 = *(f16x8*)&Al[cur][a_rd0];
            f16x8 al1 = *(f16x8*)&Al[cur][a_rd1];
            f16x8 bl0 = *(f16x8*)&Bl[cur][b_rd0];
            f16x8 bl1 = *(f16x8*)&Bl[cur][b_rd1];
            accm[0][0] = __builtin_amdgcn_mfma_f32_16x16x32_f16(ah0, bh0, accm[0][0], 0, 0, 0);
            accm[0][1] = __builtin_amdgcn_mfma_f32_16x16x32_f16(ah0, bh1, accm[0][1], 0, 0, 0);
            accm[1][0] = __builtin_amdgcn_mfma_f32_16x16x32_f16(ah1, bh0, accm[1][0], 0, 0, 0);
            accm[1][1] = __builtin_amdgcn_mfma_f32_16x16x32_f16(ah1, bh1, accm[1][1], 0, 0, 0);
            accc[0][0] = __builtin_amdgcn_mfma_f32_16x16x32_f16(ah0, bl0, accc[0][0], 0, 0, 0);
            accc[0][1] = __builtin_amdgcn_mfma_f32_16x16x32_f16(ah0, bl1, accc[0][1], 0, 0, 0);
            accc[1][0] = __builtin_amdgcn_mfma_f32_16x16x32_f16(ah1, bl0, accc[1][0], 0, 0, 0);
            accc[1][1] = __builtin_amdgcn_mfma_f32_16x16x32_f16(ah1, bl1, accc[1][1], 0, 0, 0);
            accc[0][0] = __builtin_amdgcn_mfma_f32_16x16x32_f16(al0, bh0, accc[0][0], 0, 0, 0);
            accc[0][1] = __builtin_amdgcn_mfma_f32_16x16x32_f16(al0, bh1, accc[0][1], 0, 0, 0);
            accc[1][0] = __builtin_amdgcn_mfma_f32_16x16x32_f16(al1, bh0, accc[1][0], 0, 0, 0);
            accc[1][1] = __builtin_amdgcn_mfma_f32_16x16x32_f16(al1, bh1, accc[1][1], 0, 0, 0);
        }
        if (t + 1 < nt) {
            STORE(cur ^ 1);
            __syncthreads();
        }
    }

    const float inv = 1.0f / 4096.0f;
    #pragma unroll
    for (int mi = 0; mi < 2; ++mi) {
        #pragma unroll
        for (int r = 0; r < 4; ++r) {
            int row = m0 + wr + mi * 16 + lhi * 4 + r;
            if (row < M) {
                #pragma unroll
                for (int ni = 0; ni < 2; ++ni) {
                    int col = n0 + wc + ni * 16 + llo;
                    float v = accm[mi][ni][r] + accc[mi][ni][r] * inv;
                    P[(size_t)kz * 1048576 + (size_t)row * 1024 + col] = v;
                }
            }
        }
    }
}

// ---------------- fuse: out = relu(P0 + P1 + bias), 1000x1024 ----------------
__global__ __launch_bounds__(256) void k_fuse(const float* __restrict__ P,
                                              const float* __restrict__ bias,
                                              float* __restrict__ out) {
    int t = blockIdx.x * 256 + threadIdx.x;   // float4 index, 0..255999
    float4 p0 = ((const float4*)P)[t];
    float4 p1 = ((const float4*)(P + 1048576))[t];
    float4 b  = ((const float4*)bias)[t & 255];
    float4 v;
    v.x = fmaxf(p0.x + p1.x + b.x, 0.f);
    v.y = fmaxf(p0.y + p1.y + b.y, 0.f);
    v.z = fmaxf(p0.z + p1.z + b.z, 0.f);
    v.w = fmaxf(p0.w + p1.w + b.w, 0.f);
    ((float4*)out)[t] = v;
}

// ---------------- heads: logits[1000][105] = x2 @ [wc|wb] + [bc|bb] ----------------
__global__ __launch_bounds__(128) void k_heads(const float* __restrict__ x2,
                                               const float* __restrict__ wc,
                                               const float* __restrict__ bc,
                                               const float* __restrict__ wb,
                                               const float* __restrict__ bb,
                                               float* __restrict__ logits) {
    int r0 = blockIdx.x * 4;
    __shared__ float xs[4][HID];
    for (int i = threadIdx.x; i < 4 * HID; i += 128) {
        int rr = i >> 10, kk = i & 1023;
        xs[rr][kk] = x2[(size_t)(r0 + rr) * HID + kk];
    }
    __syncthreads();
    int j = threadIdx.x;
    if (j < NHEAD) {
        float a0 = 0.f, a1 = 0.f, a2 = 0.f, a3 = 0.f;
        if (j < NCLS) {
            for (int k = 0; k < HID; ++k) {
                float w = wc[k * NCLS + j];
                a0 = fmaf(xs[0][k], w, a0);
                a1 = fmaf(xs[1][k], w, a1);
                a2 = fmaf(xs[2][k], w, a2);
                a3 = fmaf(xs[3][k], w, a3);
            }
            float b = bc[j];
            a0 += b; a1 += b; a2 += b; a3 += b;
        } else {
            int jb = j - NCLS;
            for (int k = 0; k < HID; ++k) {
                float w = wb[k * 84 + jb];
                a0 = fmaf(xs[0][k], w, a0);
                a1 = fmaf(xs[1][k], w, a1);
                a2 = fmaf(xs[2][k], w, a2);
                a3 = fmaf(xs[3][k], w, a3);
            }
            float b = bb[jb];
            a0 += b; a1 += b; a2 += b; a3 += b;
        }
        logits[(size_t)(r0 + 0) * NHEAD + j] = a0;
        logits[(size_t)(r0 + 1) * NHEAD + j] = a1;
        logits[(size_t)(r0 + 2) * NHEAD + j] = a2;
        logits[(size_t)(r0 + 3) * NHEAD + j] = a3;
    }
}

// ---------------- softmax + decode + candidate scores ----------------
__global__ __launch_bounds__(256) void k_prep(const float* __restrict__ logits,
                                              const float* __restrict__ rois,
                                              float* __restrict__ boxes,
                                              float* __restrict__ cand) {
    int n = blockIdx.x * 256 + threadIdx.x;
    if (n >= NPROP) return;
    const float* L = logits + (size_t)n * NHEAD;
    float m = L[0];
    #pragma unroll
    for (int k = 1; k < NCLS; ++k) m = fmaxf(m, L[k]);
    float sum = 0.f;
    #pragma unroll
    for (int k = 0; k < NCLS; ++k) sum += expf(L[k] - m);

    float p0 = rois[n * 4 + 0], p1 = rois[n * 4 + 1];
    float p2 = rois[n * 4 + 2], p3 = rois[n * 4 + 3];
    float w = p2 - p0, h = p3 - p1;
    float cx = p0 + 0.5f * w, cy = p1 + 0.5f * h;

    for (int k = 1; k < NCLS; ++k) {
        int i = n * 20 + (k - 1);
        float s = expf(L[k] - m) / sum;
        const float* D = L + NCLS + k * 4;
        float dx = D[0], dy = D[1], dw = D[2], dh = D[3];
        float pcx = dx * w + cx;
        float pcy = dy * h + cy;
        float pw = expf(dw) * w;
        float ph = expf(dh) * h;
        boxes[(size_t)i * 4 + 0] = pcx - 0.5f * pw;
        boxes[(size_t)i * 4 + 1] = pcy - 0.5f * ph;
        boxes[(size_t)i * 4 + 2] = pcx + 0.5f * pw;
        boxes[(size_t)i * 4 + 3] = pcy + 0.5f * ph;
        cand[i] = (s > SCORE_T) ? s : -__builtin_inff();
    }
}

// ---------------- NMS: single block, register scores + LDS compacted boxes ----------------
__global__ __launch_bounds__(1024) void k_nms(const float* __restrict__ cand,
                                              const float* __restrict__ boxes,
                                              float* __restrict__ out) {
    __shared__ float4 cb[NMS_CAP];           // compacted boxes_off (label*1e4 pre-added)
    __shared__ unsigned long long gkeys[2];  // ping-pong argmax keys
    __shared__ int cnt;
    __shared__ float sb[4];                  // winner box_off broadcast
    int tid = threadIdx.x;
    int base = tid * 20;
    if (tid == 0) cnt = 0;
    if (tid < 2) gkeys[tid] = 0ULL;
    __syncthreads();

    float s[20];
    int slot[20];
    #pragma unroll
    for (int i = 0; i < 20; ++i) {
        float v = cand[base + i];
        s[i] = v;
        slot[i] = -1;
        if (v > 0.0f) {
            int sl = atomicAdd(&cnt, 1);
            slot[i] = sl;
            float offv = (float)(i + 1) * 10000.0f;
            if (sl < NMS_CAP) {
                float4 b;
                b.x = boxes[(size_t)(base + i) * 4 + 0] + offv;
                b.y = boxes[(size_t)(base + i) * 4 + 1] + offv;
                b.z = boxes[(size_t)(base + i) * 4 + 2] + offv;
                b.w = boxes[(size_t)(base + i) * 4 + 3] + offv;
                cb[sl] = b;
            }
        }
    }
    __syncthreads();

    int cur = 0;
    int it = 0;
    for (; it < MAXDET; ++it) {
        unsigned long long key = 0ULL;
        #pragma unroll
        for (int i = 0; i < 20; ++i) {
            if (s[i] > 0.0f) {
                unsigned long long k =
                    ((unsigned long long)__float_as_uint(s[i]) << 32) |
                    (unsigned long long)(0xFFFFFFFFu - (unsigned)(base + i));
                if (k > key) key = k;
            }
        }
        #pragma unroll
        for (int off = 32; off > 0; off >>= 1) {
            unsigned long long o = __shfl_down(key, off);
            if (o > key) key = o;
        }
        if ((tid & 63) == 0) atomicMax(&gkeys[cur], key);
        __syncthreads();
        unsigned long long g = gkeys[cur];
        if (tid == 0) gkeys[cur ^ 1] = 0ULL;
        if (g != 0ULL) {
            int bi = (int)(0xFFFFFFFFu - (unsigned)(g & 0xFFFFFFFFu));
            if (bi / 20 == tid) {
                int li = bi - base;
                float bs = __uint_as_float((unsigned)(g >> 32));
                float b0 = boxes[(size_t)bi * 4 + 0];
                float b1 = boxes[(size_t)bi * 4 + 1];
                float b2 = boxes[(size_t)bi * 4 + 2];
                float b3 = boxes[(size_t)bi * 4 + 3];
                out[it * 4 + 0] = b0; out[it * 4 + 1] = b1;
                out[it * 4 + 2] = b2; out[it * 4 + 3] = b3;
                out[400 + it] = bs;
                out[500 + it] = (float)(li + 1);
                float offv = (float)(li + 1) * 10000.0f;
                sb[0] = b0 + offv; sb[1] = b1 + offv;
                sb[2] = b2 + offv; sb[3] = b3 + offv;
            }
        }
        __syncthreads();
        if (g == 0ULL) break;

        float q0 = sb[0], q1 = sb[1], q2 = sb[2], q3 = sb[3];
        float qa = (q2 - q0) * (q3 - q1);
        #pragma unroll
        for (int i = 0; i < 20; ++i) {
            if (s[i] > 0.0f) {
                float c0, c1, c2, c3;
                int sl = slot[i];
                if (sl < NMS_CAP) {
                    float4 b = cb[sl];
                    c0 = b.x; c1 = b.y; c2 = b.z; c3 = b.w;
                } else {
                    float offv = (float)(i + 1) * 10000.0f;
                    c0 = boxes[(size_t)(base + i) * 4 + 0] + offv;
                    c1 = boxes[(size_t)(base + i) * 4 + 1] + offv;
                    c2 = boxes[(size_t)(base + i) * 4 + 2] + offv;
                    c3 = boxes[(size_t)(base + i) * 4 + 3] + offv;
                }
                float ix1 = fmaxf(q0, c0), iy1 = fmaxf(q1, c1);
                float ix2 = fminf(q2, c2), iy2 = fminf(q3, c3);
                float inter = fmaxf(ix2 - ix1, 0.f) * fmaxf(iy2 - iy1, 0.f);
                float A2 = (c2 - c0) * (c3 - c1);
                float iou = inter / (qa + A2 - inter + 1e-9f);
                if (iou > NMS_T) s[i] = -__builtin_inff();
            }
        }
        cur ^= 1;
    }

    for (int j = it * 4 + tid; j < 400; j += 1024) out[j] = 0.f;
    for (int j = 400 + it + tid; j < 500; j += 1024) out[j] = 0.f;
    for (int j = 500 + it + tid; j < 600; j += 1024) out[j] = 0.f;
}

extern "C" void kernel_launch(void* const* d_in, const int* in_sizes, int n_in,
                              void* d_out, int out_size, void* d_ws, size_t ws_size,
                              hipStream_t stream) {
    const float* fm   = (const float*)d_in[0];
    const float* rois = (const float*)d_in[1];
    const float* w1   = (const float*)d_in[2];
    const float* b1   = (const float*)d_in[3];
    const float* w2   = (const float*)d_in[4];
    const float* b2   = (const float*)d_in[5];
    const float* wc   = (const float*)d_in[6];
    const float* bc   = (const float*)d_in[7];
    const float* wb   = (const float*)d_in[8];
    const float* bb   = (const float*)d_in[9];
    float* out = (float*)d_out;

    float* ws = (float*)d_ws;
    float* fmT    = ws;                       // 2,560,000 floats (also reused as P)
    float* P      = ws;                       // 2 x 1,048,576 partials (GEMM split-K)
    float* pooled = fmT + 2560000;            // 12,544,000
    float* x1     = pooled + 12544000;        // 1,024,000
    float* x2     = x1 + 1024000;             // 1,024,000
    float* logits = x2 + 1024000;             // 105,000
    float* boxes  = logits + 105000;          // 80,000
    float* cand   = boxes + 80000;            // 20,000

    k_transpose<<<157, 256, 0, stream>>>(fm, fmT);
    k_roi<<<NPROP, 256, 0, stream>>>(fmT, rois, pooled);
    k_gemm_mfma<<<dim3(16, 16, 2), 256, 0, stream>>>(pooled, w1, P, NPROP, FEAT, 196);
    k_fuse<<<1000, 256, 0, stream>>>(P, b1, x1);
    k_gemm_mfma<<<dim3(16, 16, 2), 256, 0, stream>>>(x1, w2, P, NPROP, HID, 16);
    k_fuse<<<1000, 256, 0, stream>>>(P, b2, x2);
    k_heads<<<250, 128, 0, stream>>>(x2, wc, bc, wb, bb, logits);
    k_prep<<<4, 256, 0, stream>>>(logits, rois, boxes, cand);
    k_nms<<<1, 1024, 0, stream>>>(cand, boxes, out);
}

// Round 4
// 797.319 us; speedup vs baseline: 3.0387x; 1.5943x over previous
//
#include <hip/hip_runtime.h>
#include <math.h>

#define NPROP 1000
#define CCH 256
#define FH 100
#define FW 100
#define POOLSZ 7
#define FEAT 12544   // 256*49
#define HID 1024
#define NCLS 21
#define NHEAD 105    // 21 + 84
#define NCAND 20000  // 1000 * 20
#define SCORE_T 0.05f
#define NMS_T 0.5f
#define MAXDET 100

typedef _Float16 f16;
typedef __attribute__((ext_vector_type(8))) _Float16 f16x8;
typedef __attribute__((ext_vector_type(4))) float f32x4;

// ---------------- transpose fm [256,100,100] -> fmT [100*100, 256] ----------------
__global__ __launch_bounds__(256) void k_transpose(const float* __restrict__ fm,
                                                   float* __restrict__ fmT) {
    __shared__ float lds[64 * 257];
    int posbase = blockIdx.x * 64;
    int tid = threadIdx.x;
    int cq = tid >> 6;   // 0..3
    int pl = tid & 63;   // 0..63
    int pos = posbase + pl;
    bool pok = pos < FH * FW;
    for (int c0 = 0; c0 < CCH; c0 += 4) {
        int c = c0 + cq;
        float v = pok ? fm[c * (FH * FW) + pos] : 0.f;
        lds[pl * 257 + c] = v;
    }
    __syncthreads();
    for (int p = 0; p < 64; ++p) {
        int pos2 = posbase + p;
        if (pos2 < FH * FW) fmT[(size_t)pos2 * CCH + tid] = lds[p * 257 + tid];
    }
}

// ---------------- ROI align: pooled [1000][12544], k = c*49 + py*7 + px ----------------
__global__ __launch_bounds__(256) void k_roi(const float* __restrict__ fmT,
                                             const float* __restrict__ rois,
                                             float* __restrict__ pooled) {
    int n = blockIdx.x;
    int tid = threadIdx.x;
    __shared__ float wx0[14], wx1[14], wy0[14], wy1[14];
    __shared__ int ix0[14], ix1[14], iy0[14], iy1[14], vx[14], vy[14];
    __shared__ float outb[FEAT];

    if (tid < 28) {
        int axis = tid / 14;  // 0=x, 1=y
        int j = tid % 14;
        float p0 = rois[n * 4 + axis];
        float p1 = rois[n * 4 + 2 + axis];
        float b0 = p0 * 0.125f - 0.5f;
        float b1 = p1 * 0.125f - 0.5f;
        float bsz = (b1 - b0) / 7.0f;
        int p = j >> 1, s = j & 1;
        float off = (float)p + ((float)s + 0.5f) / 2.0f;
        float v = b0 + off * bsz;
        float size = 100.0f;
        int valid = (v >= -1.0f && v <= size) ? 1 : 0;
        v = fminf(fmaxf(v, 0.0f), size - 1.0f);
        float v0 = floorf(v);
        int i0 = (int)v0;
        int i1 = min(i0 + 1, 99);
        float w1v = v - v0;
        float w0v = 1.0f - w1v;
        if (axis == 0) { ix0[j] = i0 * CCH; ix1[j] = i1 * CCH; wx0[j] = w0v; wx1[j] = w1v; vx[j] = valid; }
        else           { iy0[j] = i0 * (FW * CCH); iy1[j] = i1 * (FW * CCH); wy0[j] = w0v; wy1[j] = w1v; vy[j] = valid; }
    }
    __syncthreads();

    int c = tid;
    for (int py = 0; py < POOLSZ; ++py) {
        for (int px = 0; px < POOLSZ; ++px) {
            float acc = 0.f;
            #pragma unroll
            for (int sy = 0; sy < 2; ++sy) {
                int jy = py * 2 + sy;
                if (!vy[jy]) continue;
                float fy0 = wy0[jy], fy1 = wy1[jy];
                int y0 = iy0[jy], y1 = iy1[jy];
                #pragma unroll
                for (int sx = 0; sx < 2; ++sx) {
                    int jx = px * 2 + sx;
                    if (!vx[jx]) continue;
                    float fx0 = wx0[jx], fx1 = wx1[jx];
                    int x0 = ix0[jx], x1 = ix1[jx];
                    float a00 = fmT[y0 + x0 + c];
                    float a01 = fmT[y0 + x1 + c];
                    float a10 = fmT[y1 + x0 + c];
                    float a11 = fmT[y1 + x1 + c];
                    acc += fy0 * (fx0 * a00 + fx1 * a01) + fy1 * (fx0 * a10 + fx1 * a11);
                }
            }
            outb[c * 49 + py * 7 + px] = acc * 0.25f;
        }
    }
    __syncthreads();
    size_t base = (size_t)n * FEAT;
    for (int o = tid; o < FEAT; o += 256)
        pooled[base + o] = outb[o];
}

// ---------------- MFMA GEMM, f16 3-pass split (fp32-class accuracy) ----------------
__global__ __launch_bounds__(256) void k_gemm_mfma(const float* __restrict__ A,
                                                   const float* __restrict__ B,
                                                   float* __restrict__ P,
                                                   int M, int K, int nt) {
    __shared__ f16 Ah[2][2048], Al[2][2048], Bh[2][2048], Bl[2][2048];
    int tid = threadIdx.x;
    int n0 = blockIdx.x * 64;
    int m0 = blockIdx.y * 64;
    int kz = blockIdx.z;
    int kbase0 = kz * nt * 32;

    int a_row = tid >> 2;   // 0..63
    int a_kq  = tid & 3;    // 0..3 (8 k's each)
    int b_n   = tid & 63;
    int b_kg  = tid >> 6;   // == wave id

    int wave = tid >> 6, lane = tid & 63;
    int wr = (wave >> 1) * 32, wc = (wave & 1) * 32;
    int lhi = lane >> 4, llo = lane & 15;

    f32x4 accm[2][2] = {};
    f32x4 accc[2][2] = {};

    float aS[8], bS[8];
    const float* Arow = A + (size_t)(m0 + a_row) * K;
    bool arow_ok = (m0 + a_row) < M;

    int a_st = a_kq * 512 + ((a_row ^ a_kq) << 3);
    int b_st = b_kg * 512 + (b_n << 3);
    int a_rd0 = lhi * 512 + (((wr + 0  + llo) ^ lhi) << 3);
    int a_rd1 = lhi * 512 + (((wr + 16 + llo) ^ lhi) << 3);
    int b_rd0 = lhi * 512 + ((wc + 0  + llo) << 3);
    int b_rd1 = lhi * 512 + ((wc + 16 + llo) << 3);

    auto LOAD = [&](int t) {
        int kb = kbase0 + t * 32;
        if (arow_ok) {
            const float* ap = Arow + kb + a_kq * 8;
            float4 v0 = *(const float4*)(ap);
            float4 v1 = *(const float4*)(ap + 4);
            aS[0] = v0.x; aS[1] = v0.y; aS[2] = v0.z; aS[3] = v0.w;
            aS[4] = v1.x; aS[5] = v1.y; aS[6] = v1.z; aS[7] = v1.w;
        } else {
            #pragma unroll
            for (int j = 0; j < 8; ++j) aS[j] = 0.f;
        }
        const float* bp = B + (size_t)(kb + b_kg * 8) * 1024 + n0 + b_n;
        #pragma unroll
        for (int j = 0; j < 8; ++j) bS[j] = bp[(size_t)j * 1024];
    };
    auto STORE = [&](int buf) {
        f16x8 vh, vl;
        #pragma unroll
        for (int j = 0; j < 8; ++j) {
            f16 h = (f16)aS[j];
            vh[j] = h;
            vl[j] = (f16)((aS[j] - (float)h) * 4096.0f);
        }
        *(f16x8*)&Ah[buf][a_st] = vh;
        *(f16x8*)&Al[buf][a_st] = vl;
        #pragma unroll
        for (int j = 0; j < 8; ++j) {
            f16 h = (f16)bS[j];
            vh[j] = h;
            vl[j] = (f16)((bS[j] - (float)h) * 4096.0f);
        }
        *(f16x8*)&Bh[buf][b_st] = vh;
        *(f16x8*)&Bl[buf][b_st] = vl;
    };

    LOAD(0);
    STORE(0);
    __syncthreads();

    for (int t = 0; t < nt; ++t) {
        int cur = t & 1;
        if (t + 1 < nt) LOAD(t + 1);
        {
            f16x8 ah0 = *(f16x8*)&Ah[cur][a_rd0];
            f16x8 ah1 = *(f16x8*)&Ah[cur][a_rd1];
            f16x8 bh0 = *(f16x8*)&Bh[cur][b_rd0];
            f16x8 bh1 = *(f16x8*)&Bh[cur][b_rd1];
            f16x8 al0 = *(f16x8*)&Al[cur][a_rd0];
            f16x8 al1 = *(f16x8*)&Al[cur][a_rd1];
            f16x8 bl0 = *(f16x8*)&Bl[cur][b_rd0];
            f16x8 bl1 = *(f16x8*)&Bl[cur][b_rd1];
            accm[0][0] = __builtin_amdgcn_mfma_f32_16x16x32_f16(ah0, bh0, accm[0][0], 0, 0, 0);
            accm[0][1] = __builtin_amdgcn_mfma_f32_16x16x32_f16(ah0, bh1, accm[0][1], 0, 0, 0);
            accm[1][0] = __builtin_amdgcn_mfma_f32_16x16x32_f16(ah1, bh0, accm[1][0], 0, 0, 0);
            accm[1][1] = __builtin_amdgcn_mfma_f32_16x16x32_f16(ah1, bh1, accm[1][1], 0, 0, 0);
            accc[0][0] = __builtin_amdgcn_mfma_f32_16x16x32_f16(ah0, bl0, accc[0][0], 0, 0, 0);
            accc[0][1] = __builtin_amdgcn_mfma_f32_16x16x32_f16(ah0, bl1, accc[0][1], 0, 0, 0);
            accc[1][0] = __builtin_amdgcn_mfma_f32_16x16x32_f16(ah1, bl0, accc[1][0], 0, 0, 0);
            accc[1][1] = __builtin_amdgcn_mfma_f32_16x16x32_f16(ah1, bl1, accc[1][1], 0, 0, 0);
            accc[0][0] = __builtin_amdgcn_mfma_f32_16x16x32_f16(al0, bh0, accc[0][0], 0, 0, 0);
            accc[0][1] = __builtin_amdgcn_mfma_f32_16x16x32_f16(al0, bh1, accc[0][1], 0, 0, 0);
            accc[1][0] = __builtin_amdgcn_mfma_f32_16x16x32_f16(al1, bh0, accc[1][0], 0, 0, 0);
            accc[1][1] = __builtin_amdgcn_mfma_f32_16x16x32_f16(al1, bh1, accc[1][1], 0, 0, 0);
        }
        if (t + 1 < nt) {
            STORE(cur ^ 1);
            __syncthreads();
        }
    }

    const float inv = 1.0f / 4096.0f;
    #pragma unroll
    for (int mi = 0; mi < 2; ++mi) {
        #pragma unroll
        for (int r = 0; r < 4; ++r) {
            int row = m0 + wr + mi * 16 + lhi * 4 + r;
            if (row < M) {
                #pragma unroll
                for (int ni = 0; ni < 2; ++ni) {
                    int col = n0 + wc + ni * 16 + llo;
                    float v = accm[mi][ni][r] + accc[mi][ni][r] * inv;
                    P[(size_t)kz * 1048576 + (size_t)row * 1024 + col] = v;
                }
            }
        }
    }
}

// ---------------- fuse: out = relu(P0 + P1 + bias), 1000x1024 ----------------
__global__ __launch_bounds__(256) void k_fuse(const float* __restrict__ P,
                                              const float* __restrict__ bias,
                                              float* __restrict__ out) {
    int t = blockIdx.x * 256 + threadIdx.x;   // float4 index, 0..255999
    float4 p0 = ((const float4*)P)[t];
    float4 p1 = ((const float4*)(P + 1048576))[t];
    float4 b  = ((const float4*)bias)[t & 255];
    float4 v;
    v.x = fmaxf(p0.x + p1.x + b.x, 0.f);
    v.y = fmaxf(p0.y + p1.y + b.y, 0.f);
    v.z = fmaxf(p0.z + p1.z + b.z, 0.f);
    v.w = fmaxf(p0.w + p1.w + b.w, 0.f);
    ((float4*)out)[t] = v;
}

// ---------------- heads: logits[1000][105] = x2 @ [wc|wb] + [bc|bb] ----------------
__global__ __launch_bounds__(128) void k_heads(const float* __restrict__ x2,
                                               const float* __restrict__ wc,
                                               const float* __restrict__ bc,
                                               const float* __restrict__ wb,
                                               const float* __restrict__ bb,
                                               float* __restrict__ logits) {
    int r0 = blockIdx.x * 4;
    __shared__ float xs[4][HID];
    for (int i = threadIdx.x; i < 4 * HID; i += 128) {
        int rr = i >> 10, kk = i & 1023;
        xs[rr][kk] = x2[(size_t)(r0 + rr) * HID + kk];
    }
    __syncthreads();
    int j = threadIdx.x;
    if (j < NHEAD) {
        float a0 = 0.f, a1 = 0.f, a2 = 0.f, a3 = 0.f;
        if (j < NCLS) {
            for (int k = 0; k < HID; ++k) {
                float w = wc[k * NCLS + j];
                a0 = fmaf(xs[0][k], w, a0);
                a1 = fmaf(xs[1][k], w, a1);
                a2 = fmaf(xs[2][k], w, a2);
                a3 = fmaf(xs[3][k], w, a3);
            }
            float b = bc[j];
            a0 += b; a1 += b; a2 += b; a3 += b;
        } else {
            int jb = j - NCLS;
            for (int k = 0; k < HID; ++k) {
                float w = wb[k * 84 + jb];
                a0 = fmaf(xs[0][k], w, a0);
                a1 = fmaf(xs[1][k], w, a1);
                a2 = fmaf(xs[2][k], w, a2);
                a3 = fmaf(xs[3][k], w, a3);
            }
            float b = bb[jb];
            a0 += b; a1 += b; a2 += b; a3 += b;
        }
        logits[(size_t)(r0 + 0) * NHEAD + j] = a0;
        logits[(size_t)(r0 + 1) * NHEAD + j] = a1;
        logits[(size_t)(r0 + 2) * NHEAD + j] = a2;
        logits[(size_t)(r0 + 3) * NHEAD + j] = a3;
    }
}

// ---------------- softmax + decode + candidates + class-major offset boxes ----------------
__global__ __launch_bounds__(256) void k_prep(const float* __restrict__ logits,
                                              const float* __restrict__ rois,
                                              float* __restrict__ boxes,
                                              float* __restrict__ cand,
                                              float* __restrict__ boxesT) {
    int n = blockIdx.x * 256 + threadIdx.x;
    if (n >= NPROP) return;
    const float* L = logits + (size_t)n * NHEAD;
    float m = L[0];
    #pragma unroll
    for (int k = 1; k < NCLS; ++k) m = fmaxf(m, L[k]);
    float sum = 0.f;
    #pragma unroll
    for (int k = 0; k < NCLS; ++k) sum += expf(L[k] - m);

    float p0 = rois[n * 4 + 0], p1 = rois[n * 4 + 1];
    float p2 = rois[n * 4 + 2], p3 = rois[n * 4 + 3];
    float w = p2 - p0, h = p3 - p1;
    float cx = p0 + 0.5f * w, cy = p1 + 0.5f * h;

    for (int k = 1; k < NCLS; ++k) {
        int i = n * 20 + (k - 1);
        float s = expf(L[k] - m) / sum;
        const float* D = L + NCLS + k * 4;
        float dx = D[0], dy = D[1], dw = D[2], dh = D[3];
        float pcx = dx * w + cx;
        float pcy = dy * h + cy;
        float pw = expf(dw) * w;
        float ph = expf(dh) * h;
        float b0 = pcx - 0.5f * pw;
        float b1 = pcy - 0.5f * ph;
        float b2 = pcx + 0.5f * pw;
        float b3 = pcy + 0.5f * ph;
        boxes[(size_t)i * 4 + 0] = b0;
        boxes[(size_t)i * 4 + 1] = b1;
        boxes[(size_t)i * 4 + 2] = b2;
        boxes[(size_t)i * 4 + 3] = b3;
        cand[i] = (s > SCORE_T) ? s : -__builtin_inff();
        float offv = (float)k * 10000.0f;   // label = k, same f32 ops as reference
        ((float4*)boxesT)[(k - 1) * 1024 + n] =
            make_float4(b0 + offv, b1 + offv, b2 + offv, b3 + offv);
    }
}

// ---------------- NMS: class-major LDS scores, cached per-thread argmax key ----------------
// Key: (score_bits << 32) | (~idx) — positive-float bits monotonic; tie -> lowest idx
// (jnp.argmax first-max). Cross-class suppression impossible (offsets 10000 apart,
// boxes span <~1000), so each iteration tests exactly one candidate per thread.
__global__ __launch_bounds__(1024) void k_nms(const float* __restrict__ cand,
                                              const float* __restrict__ boxes,
                                              const float* __restrict__ boxesT,
                                              float* __restrict__ out) {
    __shared__ float s_lds[20 * 1024];          // class-major scores [cls][tid]
    __shared__ unsigned long long gkeys[2];     // ping-pong global argmax
    __shared__ unsigned long long wkeys[MAXDET];// deferred winners
    __shared__ float sb[4];                     // winner offset box
    int tid = threadIdx.x;
    if (tid < 2) gkeys[tid] = 0ULL;
    if (tid < MAXDET) wkeys[tid] = 0ULL;

    unsigned long long tkey = 0ULL;
    if (tid < NPROP) {
        #pragma unroll
        for (int i = 0; i < 20; ++i) {
            float v = cand[tid * 20 + i];
            s_lds[i * 1024 + tid] = v;
            if (v > 0.0f) {
                unsigned long long k =
                    ((unsigned long long)__float_as_uint(v) << 32) |
                    (unsigned long long)(0xFFFFFFFFu - (unsigned)(tid * 20 + i));
                if (k > tkey) tkey = k;
            }
        }
    } else {
        #pragma unroll
        for (int i = 0; i < 20; ++i) s_lds[i * 1024 + tid] = -__builtin_inff();
    }
    __syncthreads();

    for (int it = 0; it < MAXDET; ++it) {
        int cur = it & 1;
        unsigned long long k = tkey;
        #pragma unroll
        for (int off = 32; off > 0; off >>= 1) {
            unsigned long long o = __shfl_down(k, off);
            if (o > k) k = o;
        }
        if ((tid & 63) == 0) atomicMax(&gkeys[cur], k);
        __syncthreads();   // A: argmax complete
        unsigned long long g = gkeys[cur];
        int bi = (int)(0xFFFFFFFFu - (unsigned)(g & 0xFFFFFFFFu));
        int own = bi / 20;
        int wcls = bi - own * 20;
        if (tid == 0) {
            gkeys[cur ^ 1] = 0ULL;   // reset other buffer for next iteration
            wkeys[it] = g;           // defer output (0 = invalid)
        }
        if (g != 0ULL && own == tid) {
            float4 b = ((const float4*)boxesT)[wcls * 1024 + tid];
            sb[0] = b.x; sb[1] = b.y; sb[2] = b.z; sb[3] = b.w;
        }
        __syncthreads();   // B: sb + resets visible
        if (g == 0ULL) break;  // uniform: nothing above SCORE_T remains -> zeros forever

        // suppress: only my candidate of the winner's class can be affected
        float sv = s_lds[wcls * 1024 + tid];
        bool killed = false;
        if (sv > 0.0f) {
            float4 c = ((const float4*)boxesT)[wcls * 1024 + tid];
            float q0 = sb[0], q1 = sb[1], q2 = sb[2], q3 = sb[3];
            float qa = (q2 - q0) * (q3 - q1);
            float ix1 = fmaxf(q0, c.x), iy1 = fmaxf(q1, c.y);
            float ix2 = fminf(q2, c.z), iy2 = fminf(q3, c.w);
            float inter = fmaxf(ix2 - ix1, 0.f) * fmaxf(iy2 - iy1, 0.f);
            float A2 = (c.z - c.x) * (c.w - c.y);
            float iou = inter / (qa + A2 - inter + 1e-9f);
            if (iou > NMS_T) {
                s_lds[wcls * 1024 + tid] = -__builtin_inff();
                killed = true;
            }
        }
        if (killed) {   // my cached argmax may be stale -> rebuild from my column
            tkey = 0ULL;
            #pragma unroll
            for (int i = 0; i < 20; ++i) {
                float v = s_lds[i * 1024 + tid];
                if (v > 0.0f) {
                    unsigned long long kk =
                        ((unsigned long long)__float_as_uint(v) << 32) |
                        (unsigned long long)(0xFFFFFFFFu - (unsigned)(tid * 20 + i));
                    if (kk > tkey) tkey = kk;
                }
            }
        }
    }

    __syncthreads();
    // output phase: exact un-offset boxes from global, scores bit-exact from keys
    if (tid < MAXDET) {
        unsigned long long g = wkeys[tid];
        if (g != 0ULL) {
            int bi = (int)(0xFFFFFFFFu - (unsigned)(g & 0xFFFFFFFFu));
            float4 b = ((const float4*)boxes)[bi];
            out[tid * 4 + 0] = b.x; out[tid * 4 + 1] = b.y;
            out[tid * 4 + 2] = b.z; out[tid * 4 + 3] = b.w;
            out[400 + tid] = __uint_as_float((unsigned)(g >> 32));
            out[500 + tid] = (float)(bi - (bi / 20) * 20 + 1);
        } else {
            out[tid * 4 + 0] = 0.f; out[tid * 4 + 1] = 0.f;
            out[tid * 4 + 2] = 0.f; out[tid * 4 + 3] = 0.f;
            out[400 + tid] = 0.f;
            out[500 + tid] = 0.f;
        }
    }
}

extern "C" void kernel_launch(void* const* d_in, const int* in_sizes, int n_in,
                              void* d_out, int out_size, void* d_ws, size_t ws_size,
                              hipStream_t stream) {
    const float* fm   = (const float*)d_in[0];
    const float* rois = (const float*)d_in[1];
    const float* w1   = (const float*)d_in[2];
    const float* b1   = (const float*)d_in[3];
    const float* w2   = (const float*)d_in[4];
    const float* b2   = (const float*)d_in[5];
    const float* wc   = (const float*)d_in[6];
    const float* bc   = (const float*)d_in[7];
    const float* wb   = (const float*)d_in[8];
    const float* bb   = (const float*)d_in[9];
    float* out = (float*)d_out;

    float* ws = (float*)d_ws;
    float* fmT    = ws;                       // 2,560,000 floats (reused as P after roi)
    float* P      = ws;                       // 2 x 1,048,576 partials (GEMM split-K)
    float* pooled = fmT + 2560000;            // 12,544,000 (reused as boxesT after GEMM1)
    float* x1     = pooled + 12544000;        // 1,024,000
    float* x2     = x1 + 1024000;             // 1,024,000
    float* logits = x2 + 1024000;             // 105,000
    float* boxes  = logits + 105000;          // 80,000
    float* cand   = boxes + 80000;            // 20,000
    float* boxesT = pooled;                   // 20*1024*4 floats, class-major offset boxes

    k_transpose<<<157, 256, 0, stream>>>(fm, fmT);
    k_roi<<<NPROP, 256, 0, stream>>>(fmT, rois, pooled);
    k_gemm_mfma<<<dim3(16, 16, 2), 256, 0, stream>>>(pooled, w1, P, NPROP, FEAT, 196);
    k_fuse<<<1000, 256, 0, stream>>>(P, b1, x1);
    k_gemm_mfma<<<dim3(16, 16, 2), 256, 0, stream>>>(x1, w2, P, NPROP, HID, 16);
    k_fuse<<<1000, 256, 0, stream>>>(P, b2, x2);
    k_heads<<<250, 128, 0, stream>>>(x2, wc, bc, wb, bb, logits);
    k_prep<<<4, 256, 0, stream>>>(logits, rois, boxes, cand, boxesT);
    k_nms<<<1, 1024, 0, stream>>>(cand, boxes, boxesT, out);
}